// Round 10
// baseline (1731.039 us; speedup 1.0000x reference)
//
#include <hip/hip_runtime.h>
#include <hip/hip_bf16.h>

#define IN_F   4096
#define OUT_F  4096
#define PACKED (IN_F / 8)      // 512
#define M_DIM  8192            // 4 * 2048
#define N_DIM  4096
#define K_DIM  4096

#define BM 256
#define BN 256
#define BK 64
#define NT (K_DIM / BK)        // 64 K-tiles

typedef __bf16 bf16x8 __attribute__((ext_vector_type(8)));
typedef float  f32x4  __attribute__((ext_vector_type(4)));

#define BAR() asm volatile("s_barrier" ::: "memory")
#define VMCNT(n) asm volatile("s_waitcnt vmcnt(" #n ")" ::: "memory")
#define AS1 __attribute__((address_space(1)))
#define AS3 __attribute__((address_space(3)))

// ---------------------------------------------------------------------------
// Fragment-ordered DRAM layout for both GEMM operands (produced by prepasses):
//   [128-row-half][kTile64(64)][subtile st(16)][1024 B]
//   subtile st: rows (st>>1)*16..+15 (within the half), k-cols (st&1)*32..+31
//   within subtile, chunk l (=byte/16): row16 = l&15, k8 = (l>>4)*8
// A wave staging/reading a subtile touches a CONTIGUOUS 1 KB.
// ---------------------------------------------------------------------------

// Pre-pass 1: dequantize int4 -> bf16 fragment-ordered W.
__global__ __launch_bounds__(256) void dequant_kernel(
    const int* __restrict__ qw, const float* __restrict__ qs,
    const int* __restrict__ qz, __bf16* __restrict__ W)
{
    int ch = blockIdx.x * blockDim.x + threadIdx.x;
    if (ch >= OUT_F * PACKED) return;
    int l     = ch & 63;
    int st    = (ch >> 6) & 15;
    int kTile = (ch >> 10) & 63;
    int nHalf = ch >> 16;
    int o  = nHalf * 128 + ((st >> 1) << 4) + (l & 15);
    int k0 = kTile * 64 + ((st & 1) << 5) + ((l >> 4) << 3);
    int g  = k0 >> 7;
    unsigned int q = (unsigned int)qw[o * PACKED + (k0 >> 3)];
    float scale = qs[g * OUT_F + o];
    float zero  = (float)qz[g * OUT_F + o];
    bf16x8 v;
#pragma unroll
    for (int i = 0; i < 8; ++i) {
        float wi = (float)((q >> (4 * i)) & 15u);
        v[i] = (__bf16)((wi - zero) * scale);
    }
    *reinterpret_cast<bf16x8*>(&W[(size_t)ch * 8]) = v;
}

// Pre-pass 2: x f32 -> bf16 fragment-ordered xb.
__global__ __launch_bounds__(256) void cvt_kernel(
    const float* __restrict__ x, __bf16* __restrict__ xb, int nch)
{
    int ch = blockIdx.x * blockDim.x + threadIdx.x;
    if (ch >= nch) return;
    int l     = ch & 63;
    int st    = (ch >> 6) & 15;
    int kTile = (ch >> 10) & 63;
    int mHalf = ch >> 16;
    int m  = mHalf * 128 + ((st >> 1) << 4) + (l & 15);
    int k0 = kTile * 64 + ((st & 1) << 5) + ((l >> 4) << 3);
    const float4* xv = reinterpret_cast<const float4*>(x + (size_t)m * K_DIM + k0);
    float4 a = xv[0];
    float4 b = xv[1];
    bf16x8 v;
    v[0] = (__bf16)a.x; v[1] = (__bf16)a.y; v[2] = (__bf16)a.z; v[3] = (__bf16)a.w;
    v[4] = (__bf16)b.x; v[5] = (__bf16)b.y; v[6] = (__bf16)b.z; v[7] = (__bf16)b.w;
    reinterpret_cast<bf16x8*>(xb)[ch] = v;
}

// ---------------------------------------------------------------------------
// GEMM: 256x256 tile, BK=64, 8 waves (2Mx4N). ONE-WINDOW-AHEAD register
// pipeline: window w MFMAs tile w on fragments read during window w-1, while
// issuing ds_reads for tile w+1 and stage(w+3). A: 4-deep LDS buffers
// (128 KiB); B: direct global->VGPR (refill-after-last-use). One barrier per
// window; explicit VMCNT(12) publishes stage(w+2) cross-wave while keeping
// this window's 12 vmem ops (stage 4 + B 8) in flight.
// ---------------------------------------------------------------------------
__global__ __launch_bounds__(512, 2) void gemm_kernel(
    const __bf16* __restrict__ A, const __bf16* __restrict__ B,
    float* __restrict__ C)
{
    extern __shared__ __bf16 lds[];   // 4 bufs x 16384 bf16 (A only) = 128 KiB

    const int tid  = threadIdx.x;
    const int lane = tid & 63;
    const int wave = tid >> 6;        // 0..7
    const int wm   = wave >> 2;       // 0..1
    const int wn   = wave & 3;        // 0..3
    const int wm8  = wm * 8;
    const int wn4  = wn * 4;
    const int lane8 = lane * 8;

    // bijective XCD swizzle: 512 blocks = 8 XCDs x 64
    const int bid = blockIdx.x;
    const int swz = (bid & 7) * 64 + (bid >> 3);
    const int nBase = (swz & 15) * BN;
    const int mBase = (swz >> 4) * BM;
    const int mHalf = mBase >> 7;
    const int nHalf = nBase >> 7;

    const int lr = lane & 15;

    // stage full 256x64 A K-tile (both halves, 32 subtiles): 4 gload_lds/thread
    auto stageA = [&](int t) {
        __bf16* dst = lds + (t & 3) * 16384;
#pragma unroll
        for (int h = 0; h < 2; ++h) {
            const __bf16* src = A + ((size_t)((mHalf + h) * 64 + t) << 13);
#pragma unroll
            for (int i = 0; i < 2; ++i) {
                const int st = i * 8 + wave;      // wave-uniform
                __builtin_amdgcn_global_load_lds(
                    (const AS1 void*)(src + st * 512 + lane8),
                    (AS3 void*)(dst + h * 8192 + st * 512 + lane8), 16, 0, 0);
            }
        }
    };

    f32x4 acc[8][4];
#pragma unroll
    for (int i = 0; i < 8; ++i)
#pragma unroll
        for (int j = 0; j < 4; ++j)
            acc[i][j] = 0.0f;

    bf16x8 fXa[8][2], fXb[8][2];   // ping-pong A fragment sets
    bf16x8 Bc[4][2];               // B fragments, refill-after-last-use

// direct global B-fragment load: contiguous 1 KB per wave-instruction
#define LOADB2(njBase, tt) do { \
    _Pragma("unroll") \
    for (int _nj = 0; _nj < 2; ++_nj) { \
        const int _rb = wn4 + (njBase) + _nj; \
        _Pragma("unroll") \
        for (int _kb = 0; _kb < 2; ++_kb) { \
            const __bf16* _p = B + ((size_t)((nHalf + (_rb >> 3)) * 64 + (tt)) << 13) \
                                 + (((_rb & 7) * 2 + _kb) << 9) + lane8; \
            Bc[(njBase) + _nj][_kb] = *reinterpret_cast<const bf16x8*>(_p); \
        } \
    } \
} while (0)

// window W: MFMA tile W on X; ds_read tile W+1 into Y; stage W+3; refill B(W+1)
#define WINDOW(W, X, Y) do { \
    const int _w = (W); \
    if (_w + 1 < NT) { \
        const __bf16* _rb = lds + ((_w + 1) & 3) * 16384; \
        _Pragma("unroll") \
        for (int _mi = 0; _mi < 8; ++_mi) { \
            Y[_mi][0] = *(const bf16x8*)(_rb + (((wm8 + _mi) * 2 + 0) << 9) + lane8); \
            Y[_mi][1] = *(const bf16x8*)(_rb + (((wm8 + _mi) * 2 + 1) << 9) + lane8); \
        } \
    } \
    if (_w + 3 < NT) stageA(_w + 3); \
    __builtin_amdgcn_sched_barrier(0); \
    __builtin_amdgcn_s_setprio(1); \
    _Pragma("unroll") \
    for (int _kb = 0; _kb < 2; ++_kb) \
        _Pragma("unroll") \
        for (int _mi = 0; _mi < 8; ++_mi) \
            _Pragma("unroll") \
            for (int _nj = 0; _nj < 2; ++_nj) \
                acc[_mi][_nj] = __builtin_amdgcn_mfma_f32_16x16x32_bf16(X[_mi][_kb], Bc[_nj][_kb], acc[_mi][_nj], 0, 0, 0); \
    if (_w + 1 < NT) LOADB2(0, _w + 1); \
    _Pragma("unroll") \
    for (int _kb = 0; _kb < 2; ++_kb) \
        _Pragma("unroll") \
        for (int _mi = 0; _mi < 8; ++_mi) \
            _Pragma("unroll") \
            for (int _nj = 0; _nj < 2; ++_nj) \
                acc[_mi][_nj + 2] = __builtin_amdgcn_mfma_f32_16x16x32_bf16(X[_mi][_kb], Bc[_nj + 2][_kb], acc[_mi][_nj + 2], 0, 0, 0); \
    if (_w + 1 < NT) LOADB2(2, _w + 1); \
    __builtin_amdgcn_s_setprio(0); \
    if (_w <= NT - 4)      { VMCNT(12); BAR(); } \
    else if (_w <= NT - 2) { VMCNT(8);  BAR(); } \
} while (0)

    // Prologue: stage tiles 0,1,2 (12 vm); B(0) (8 vm); retire stages 0,1.
    stageA(0); stageA(1); stageA(2);
    LOADB2(0, 0); LOADB2(2, 0);
    VMCNT(12);                 // keep [stage(2), B(0)]; stages 0,1 published
    BAR();
    {   // reads(0) -> fXa (one-time exposed DS latency)
        const __bf16* rb = lds;
#pragma unroll
        for (int mi = 0; mi < 8; ++mi) {
            fXa[mi][0] = *(const bf16x8*)(rb + (((wm8 + mi) * 2 + 0) << 9) + lane8);
            fXa[mi][1] = *(const bf16x8*)(rb + (((wm8 + mi) * 2 + 1) << 9) + lane8);
        }
    }

    for (int w = 0; w < NT; w += 2) {
        WINDOW(w,     fXa, fXb);
        WINDOW(w + 1, fXb, fXa);
    }

    // Epilogue: C/D layout col=lane&15, row=(lane>>4)*4+reg
#pragma unroll
    for (int mi = 0; mi < 8; ++mi)
#pragma unroll
        for (int nj = 0; nj < 4; ++nj) {
            const int col = nBase + wn * 64 + nj * 16 + lr;
#pragma unroll
            for (int r = 0; r < 4; ++r) {
                const int row = mBase + wm * 128 + mi * 16 + (lane >> 4) * 4 + r;
                C[(size_t)row * N_DIM + col] = (float)(__bf16)acc[mi][nj][r];
            }
        }
#undef WINDOW
#undef LOADB2
}

extern "C" void kernel_launch(void* const* d_in, const int* in_sizes, int n_in,
                              void* d_out, int out_size, void* d_ws, size_t ws_size,
                              hipStream_t stream)
{
    const float* x       = (const float*)d_in[0];
    const int*   qweight = (const int*)d_in[1];
    const float* qscale  = (const float*)d_in[2];
    const int*   qzeros  = (const int*)d_in[3];
    float*       out     = (float*)d_out;

    __bf16* W  = (__bf16*)d_ws;
    __bf16* xb = (__bf16*)((char*)d_ws + (size_t)N_DIM * K_DIM * sizeof(__bf16));

    {
        int total = OUT_F * PACKED;
        dequant_kernel<<<(total + 255) / 256, 256, 0, stream>>>(qweight, qscale, qzeros, W);
    }
    {
        int nch = (M_DIM * K_DIM) / 8;
        cvt_kernel<<<(nch + 255) / 256, 256, 0, stream>>>(x, xb, nch);
    }
    {
        (void)hipFuncSetAttribute((const void*)gemm_kernel,
                                  hipFuncAttributeMaxDynamicSharedMemorySize, 131072);
        dim3 grid((M_DIM / BM) * (N_DIM / BN));   // 512 blocks
        gemm_kernel<<<grid, 512, 131072, stream>>>(xb, W, out);
    }
}

// Round 11
// 294.486 us; speedup vs baseline: 5.8782x; 5.8782x over previous
//
#include <hip/hip_runtime.h>
#include <hip/hip_bf16.h>

#define IN_F   4096
#define OUT_F  4096
#define PACKED (IN_F / 8)      // 512
#define M_DIM  8192            // 4 * 2048
#define N_DIM  4096
#define K_DIM  4096

#define BM 256
#define BN 256
#define BK 32
#define NT (K_DIM / BK)        // 128 K-steps

typedef __bf16 bf16x8 __attribute__((ext_vector_type(8)));
typedef float  f32x4  __attribute__((ext_vector_type(4)));

#define BAR() asm volatile("s_barrier" ::: "memory")
#define VMCNT(n) asm volatile("s_waitcnt vmcnt(" #n ")" ::: "memory")
#define LGKM0() asm volatile("s_waitcnt lgkmcnt(0)" ::: "memory")
#define AS1 __attribute__((address_space(1)))
#define AS3 __attribute__((address_space(3)))

// ---------------------------------------------------------------------------
// Fragment-ordered DRAM layout for both GEMM operands (produced by prepasses):
//   [128-row-half][kTile64(64)][subtile st(16)][1024 B]
//   subtile st: rows (st>>1)*16..+15 (within the half), k-cols (st&1)*32..+31
//   within subtile, chunk l (=byte/16): row16 = l&15, k8 = (l>>4)*8
// A wave staging/reading a subtile touches a CONTIGUOUS 1 KB. A BK=32 K-step
// uses the 16 subtiles of one 64-K-tile with matching k-parity.
// ---------------------------------------------------------------------------

// Pre-pass 1: dequantize int4 -> bf16 fragment-ordered W.
__global__ __launch_bounds__(256) void dequant_kernel(
    const int* __restrict__ qw, const float* __restrict__ qs,
    const int* __restrict__ qz, __bf16* __restrict__ W)
{
    int ch = blockIdx.x * blockDim.x + threadIdx.x;
    if (ch >= OUT_F * PACKED) return;
    int l     = ch & 63;
    int st    = (ch >> 6) & 15;
    int kTile = (ch >> 10) & 63;
    int nHalf = ch >> 16;
    int o  = nHalf * 128 + ((st >> 1) << 4) + (l & 15);
    int k0 = kTile * 64 + ((st & 1) << 5) + ((l >> 4) << 3);
    int g  = k0 >> 7;
    unsigned int q = (unsigned int)qw[o * PACKED + (k0 >> 3)];
    float scale = qs[g * OUT_F + o];
    float zero  = (float)qz[g * OUT_F + o];
    bf16x8 v;
#pragma unroll
    for (int i = 0; i < 8; ++i) {
        float wi = (float)((q >> (4 * i)) & 15u);
        v[i] = (__bf16)((wi - zero) * scale);
    }
    *reinterpret_cast<bf16x8*>(&W[(size_t)ch * 8]) = v;
}

// Pre-pass 2: x f32 -> bf16 fragment-ordered xb.
__global__ __launch_bounds__(256) void cvt_kernel(
    const float* __restrict__ x, __bf16* __restrict__ xb, int nch)
{
    int ch = blockIdx.x * blockDim.x + threadIdx.x;
    if (ch >= nch) return;
    int l     = ch & 63;
    int st    = (ch >> 6) & 15;
    int kTile = (ch >> 10) & 63;
    int mHalf = ch >> 16;
    int m  = mHalf * 128 + ((st >> 1) << 4) + (l & 15);
    int k0 = kTile * 64 + ((st & 1) << 5) + ((l >> 4) << 3);
    const float4* xv = reinterpret_cast<const float4*>(x + (size_t)m * K_DIM + k0);
    float4 a = xv[0];
    float4 b = xv[1];
    bf16x8 v;
    v[0] = (__bf16)a.x; v[1] = (__bf16)a.y; v[2] = (__bf16)a.z; v[3] = (__bf16)a.w;
    v[4] = (__bf16)b.x; v[5] = (__bf16)b.y; v[6] = (__bf16)b.z; v[7] = (__bf16)b.w;
    reinterpret_cast<bf16x8*>(xb)[ch] = v;
}

// ---------------------------------------------------------------------------
// GEMM: 256x256 tile, BK=32, 8 waves (2Mx4N, 128x64 out/wave), 4-deep LDS
// (4 x 32 KiB). GANG-STAGGERED window schedule:
//   gang A (waves 0,3,5,6): read(tile w); lgkm0 | BAR | stage; MFMA(tile w)
//   gang B (waves 1,2,4,7): MFMA(tile w, carried) | BAR | stage; read(tile w+1)
// In each half-window one gang uses the DS pipe while the other uses the
// matrix pipe. Both gangs share ONE fr[12] register set (r10's spill fix).
// Stage 3 tiles ahead; VMCNT(4) at window end retires stage(w+2).
// ---------------------------------------------------------------------------
__global__ __launch_bounds__(512, 2) void gemm_kernel(
    const __bf16* __restrict__ A, const __bf16* __restrict__ B,
    float* __restrict__ C)
{
    extern __shared__ __bf16 lds[];   // 4 bufs x 16384 elems (A 8K | B 8K) = 128 KiB

    const int tid  = threadIdx.x;
    const int lane = tid & 63;
    const int wave = tid >> 6;        // 0..7
    const int wm   = wave >> 2;       // 0..1
    const int wn   = wave & 3;        // 0..3
    const bool gangA = (0x69 >> wave) & 1;   // waves {0,3,5,6}: one per SIMD
                                             // under both wave%4 and wave/2 maps
    const int lane8 = lane * 8;

    // bijective XCD swizzle: 512 blocks = 8 XCDs x 64
    const int bid = blockIdx.x;
    const int swz = (bid & 7) * 64 + (bid >> 3);
    const int nBase = (swz & 15) * BN;
    const int mBase = (swz >> 4) * BM;
    const int mHalf = mBase >> 7;
    const int nHalf = nBase >> 7;

    const int lr = lane & 15;

    // stage one 256x32 A-step + 256x32 B-step (32 subtiles, 4 loads/thread)
    auto stage_tile = [&](int t32) {
        __bf16* dst = lds + (t32 & 3) * 16384;
        const int kT = t32 >> 1;
        const int kp = t32 & 1;
#pragma unroll
        for (int i = 0; i < 4; ++i) {
            const int s    = i * 8 + wave;    // 0..31, wave-uniform
            const int isB  = (i >> 1);        // i0,i1 -> A; i2,i3 -> B
            const int half = (i & 1);
            const int srcHalf = (isB ? nHalf : mHalf) + half;
            const __bf16* src = (isB ? B : A)
                + ((size_t)(srcHalf * 64 + kT) << 13)
                + (wave * 2 + kp) * 512;
            __builtin_amdgcn_global_load_lds(
                (const AS1 void*)(src + lane8),
                (AS3 void*)(dst + s * 512 + lane8), 16, 0, 0);
        }
    };

    f32x4 acc[8][4];
#pragma unroll
    for (int i = 0; i < 8; ++i)
#pragma unroll
        for (int j = 0; j < 4; ++j)
            acc[i][j] = 0.0f;

    bf16x8 fr[12];   // A frags [0..7], B frags [8..11] -- shared by both gangs

#define LDA_(buf, mi) (*(const bf16x8*)((buf) + ((wm * 8 + (mi)) * 512) + lane8))
#define LDB_(buf, nj) (*(const bf16x8*)((buf) + 8192 + ((wn * 4 + (nj)) * 512) + lane8))

    auto read12 = [&](const __bf16* buf) {
#pragma unroll
        for (int mi = 0; mi < 8; ++mi) fr[mi] = LDA_(buf, mi);
#pragma unroll
        for (int nj = 0; nj < 4; ++nj) fr[8 + nj] = LDB_(buf, nj);
    };
    auto mfma32 = [&]() {
        __builtin_amdgcn_s_setprio(1);
#pragma unroll
        for (int mi = 0; mi < 8; ++mi)
#pragma unroll
            for (int nj = 0; nj < 4; ++nj)
                acc[mi][nj] = __builtin_amdgcn_mfma_f32_16x16x32_bf16(
                    fr[mi], fr[8 + nj], acc[mi][nj], 0, 0, 0);
        __builtin_amdgcn_s_setprio(0);
    };

    // Prologue: stage K-steps 0,1,2; retire 0,1 (keep 2 in flight); gang B
    // preloads tile 0 fragments.
    stage_tile(0);
    stage_tile(1);
    stage_tile(2);
    VMCNT(4);
    BAR();
    if (!gangA) read12(lds);

    for (int w = 0; w < NT; ++w) {
        const __bf16* cur = lds + (w & 3) * 16384;

        // ---- first half: gang A reads (DS pipe) || gang B MFMAs (matrix pipe)
        if (gangA) {
            read12(cur);
            LGKM0();                       // drain before BAR: WAR-safe vs stage
            __builtin_amdgcn_sched_barrier(0);
        } else {
            mfma32();                      // tile w, frags carried from window w-1
        }
        BAR();

        // ---- second half: stage ahead; gang A MFMAs || gang B reads next
        if (w + 3 < NT) stage_tile(w + 3);
        __builtin_amdgcn_sched_barrier(0);
        if (gangA) {
            mfma32();                      // tile w
        } else {
            if (w + 1 < NT) read12(lds + ((w + 1) & 3) * 16384);
        }
        if (w + 4 < NT) { VMCNT(4); }      // retire stage(w+2); keep stage(w+3)
        else           { VMCNT(0); }       // tail drain
        BAR();
    }

    // Epilogue: C/D layout col=lane&15, row=(lane>>4)*4+reg
#pragma unroll
    for (int mi = 0; mi < 8; ++mi)
#pragma unroll
        for (int nj = 0; nj < 4; ++nj) {
            const int col = nBase + wn * 64 + nj * 16 + lr;
#pragma unroll
            for (int r = 0; r < 4; ++r) {
                const int row = mBase + wm * 128 + mi * 16 + (lane >> 4) * 4 + r;
                C[(size_t)row * N_DIM + col] = (float)(__bf16)acc[mi][nj][r];
            }
        }
#undef LDA_
#undef LDB_
}

extern "C" void kernel_launch(void* const* d_in, const int* in_sizes, int n_in,
                              void* d_out, int out_size, void* d_ws, size_t ws_size,
                              hipStream_t stream)
{
    const float* x       = (const float*)d_in[0];
    const int*   qweight = (const int*)d_in[1];
    const float* qscale  = (const float*)d_in[2];
    const int*   qzeros  = (const int*)d_in[3];
    float*       out     = (float*)d_out;

    __bf16* W  = (__bf16*)d_ws;
    __bf16* xb = (__bf16*)((char*)d_ws + (size_t)N_DIM * K_DIM * sizeof(__bf16));

    {
        int total = OUT_F * PACKED;
        dequant_kernel<<<(total + 255) / 256, 256, 0, stream>>>(qweight, qscale, qzeros, W);
    }
    {
        int nch = (M_DIM * K_DIM) / 8;
        cvt_kernel<<<(nch + 255) / 256, 256, 0, stream>>>(x, xb, nch);
    }
    {
        (void)hipFuncSetAttribute((const void*)gemm_kernel,
                                  hipFuncAttributeMaxDynamicSharedMemorySize, 131072);
        dim3 grid((M_DIM / BM) * (N_DIM / BN));   // 512 blocks
        gemm_kernel<<<grid, 512, 131072, stream>>>(xb, W, out);
    }
}